// Round 5
// baseline (476.614 us; speedup 1.0000x reference)
//
#include <hip/hip_runtime.h>
#include <hip/hip_fp16.h>
#include <math.h>

// GCNII forward, fp16-compressed intermediates.
//   h0 = relu(x @ Wlin + b)                       [lin0: tiled GEMM]
//   per layer l: z = 0.9*(A@h) + 0.1*x0           [gather: CSR, group-per-node]
//                h = relu(z @ W'_l)               [dense: tiled GEMM]
//   W'_l = (1-beta_l) I + beta_l W_l (premixed).
// CSR build: bucketed 3-phase sort. Edges are first partitioned into 8
// destination-range buckets as packed 8B records {row:17, col:17, w:fp16}
// written sequentially (full-line writes). hist/scatter then stream only
// their bucket slice once -> dirty cw lines stay L2-resident until full
// (fixes the 95MB WRITE_SIZE for a 12.8MB buffer seen in round 4).
// Constants: N=100000, E=1600000, H=128, D=64, L=4.

#define DD 64
#define HH 128
#define SCAN_CHUNK 1024
#define M_TILE 128
#define K_CHUNK 32

__device__ inline ushort f2h(float f) { return __half_as_ushort(__float2half(f)); }
__device__ inline float us2f(ushort u) { return __half2float(__ushort_as_half(u)); }

__global__ __launch_bounds__(256) void zero_i32(int* p, int n) {
    int i = blockIdx.x * blockDim.x + threadIdx.x;
    if (i < n) p[i] = 0;
}

// ---- bucket sizes (8 destination ranges) ----
__global__ __launch_bounds__(256) void bucket_count(const int* __restrict__ row,
                                                    int* __restrict__ bcnt,
                                                    int E, int N) {
    __shared__ int c8[8];
    int t = threadIdx.x;
    if (t < 8) c8[t] = 0;
    __syncthreads();
    for (int e = blockIdx.x * blockDim.x + t; e < E; e += gridDim.x * blockDim.x) {
        int b = (int)((8LL * row[e]) / N);
        atomicAdd(&c8[b], 1);
    }
    __syncthreads();
    if (t < 8 && c8[t] > 0) atomicAdd(&bcnt[t], c8[t]);
}

__global__ __launch_bounds__(64) void bucket_scan(const int* __restrict__ bcnt,
                                                  int* __restrict__ boff,
                                                  int* __restrict__ bcur) {
    if (threadIdx.x == 0) {
        int acc = 0;
        for (int g = 0; g < 8; ++g) {
            boff[g] = acc;
            bcur[g] = acc;
            acc += bcnt[g];
        }
        boff[8] = acc;
    }
}

// ---- partition edges into bucketed packed records ----
// pk0 = row | (col&0x7fff)<<17 ; pk1 = (col>>15) | w_fp16<<2
__global__ __launch_bounds__(256) void partition_kernel(
    const int* __restrict__ row, const int* __restrict__ col,
    const float* __restrict__ ew, int* __restrict__ bcur,
    uint* __restrict__ pk0, uint* __restrict__ pk1, int E, int N) {
    __shared__ int cnt8[8], base8[8], rc8[8];
    int t = threadIdx.x;
    if (t < 8) { cnt8[t] = 0; rc8[t] = 0; }
    __syncthreads();
    int chunk = (E + gridDim.x - 1) / gridDim.x;
    int s0 = blockIdx.x * chunk;
    int s1 = min(s0 + chunk, E);
    for (int e = s0 + t; e < s1; e += 256) {
        int b = (int)((8LL * row[e]) / N);
        atomicAdd(&cnt8[b], 1);
    }
    __syncthreads();
    if (t < 8) base8[t] = (cnt8[t] > 0) ? atomicAdd(&bcur[t], cnt8[t]) : 0;
    __syncthreads();
    for (int e = s0 + t; e < s1; e += 256) {
        int r = row[e];
        int c = col[e];
        ushort wh = f2h(ew[e]);
        int b = (int)((8LL * r) / N);
        int pos = base8[b] + atomicAdd(&rc8[b], 1);
        pk0[pos] = (uint)r | (((uint)c & 0x7fffu) << 17);
        pk1[pos] = ((uint)c >> 15) | ((uint)wh << 2);
    }
}

// ---- per-node degree histogram from bucketed records ----
__global__ __launch_bounds__(256) void hist_kernel(const uint* __restrict__ pk0,
                                                   const int* __restrict__ boff,
                                                   int* __restrict__ cnt) {
    int grp = blockIdx.x & 7;
    int bid = blockIdx.x >> 3;
    int nblk = gridDim.x >> 3;
    int lo = boff[grp], hi = boff[grp + 1];
    for (int i = lo + bid * blockDim.x + threadIdx.x; i < hi;
         i += nblk * blockDim.x)
        atomicAdd(&cnt[pk0[i] & 0x1ffffu], 1);
}

__global__ __launch_bounds__(256) void scanA(const int* __restrict__ cnt,
                                             int* __restrict__ bsum, int n) {
    __shared__ int s[256];
    int t = threadIdx.x;
    int base = blockIdx.x * SCAN_CHUNK + t * 4;
    int sum = 0;
#pragma unroll
    for (int i = 0; i < 4; ++i) {
        int idx = base + i;
        if (idx < n) sum += cnt[idx];
    }
    s[t] = sum;
    __syncthreads();
    for (int off = 128; off > 0; off >>= 1) {
        if (t < off) s[t] += s[t + off];
        __syncthreads();
    }
    if (t == 0) bsum[blockIdx.x] = s[0];
}

__global__ __launch_bounds__(64) void scanB(int* __restrict__ bsum, int nb,
                                            int* __restrict__ rowptr, int n) {
    int lane = threadIdx.x & 63;
    int i0 = 2 * lane, i1 = 2 * lane + 1;
    int a = (i0 < nb) ? bsum[i0] : 0;
    int b = (i1 < nb) ? bsum[i1] : 0;
    int s = a + b;
    for (int off = 1; off < 64; off <<= 1) {
        int t = __shfl_up(s, off);
        if (lane >= off) s += t;
    }
    int excl = s - (a + b);
    if (i0 < nb) bsum[i0] = excl;
    if (i1 < nb) bsum[i1] = excl + a;
    if (lane == 63) rowptr[n] = s;   // total == E
}

__global__ __launch_bounds__(256) void scanC(const int* __restrict__ cnt,
                                             const int* __restrict__ bsum,
                                             int* __restrict__ rowptr,
                                             int* __restrict__ fill, int n) {
    __shared__ int s[256];
    int t = threadIdx.x;
    int base = blockIdx.x * SCAN_CHUNK + t * 4;
    int v[4];
    int sum = 0;
#pragma unroll
    for (int i = 0; i < 4; ++i) {
        int idx = base + i;
        v[i] = (idx < n) ? cnt[idx] : 0;
        sum += v[i];
    }
    s[t] = sum;
    __syncthreads();
    for (int off = 1; off < 256; off <<= 1) {
        int x = (t >= off) ? s[t - off] : 0;
        __syncthreads();
        s[t] += x;
        __syncthreads();
    }
    int excl = (t == 0) ? 0 : s[t - 1];
    excl += bsum[blockIdx.x];
#pragma unroll
    for (int i = 0; i < 4; ++i) {
        int idx = base + i;
        if (idx < n) { rowptr[idx] = excl; fill[idx] = excl; excl += v[i]; }
    }
}

// ---- scatter bucketed records into CSR {col, w_f32} ----
__global__ __launch_bounds__(256) void scatter_kernel(
    const uint* __restrict__ pk0, const uint* __restrict__ pk1,
    const int* __restrict__ boff, int* __restrict__ fill,
    int2* __restrict__ cw) {
    int grp = blockIdx.x & 7;
    int bid = blockIdx.x >> 3;
    int nblk = gridDim.x >> 3;
    int lo = boff[grp], hi = boff[grp + 1];
    for (int i = lo + bid * blockDim.x + threadIdx.x; i < hi;
         i += nblk * blockDim.x) {
        uint a = pk0[i], b = pk1[i];
        int r = (int)(a & 0x1ffffu);
        int c = (int)((a >> 17) | ((b & 3u) << 15));
        float w = us2f((ushort)((b >> 2) & 0xffffu));
        int pos = atomicAdd(&fill[r], 1);
        cw[pos] = make_int2(c, __float_as_int(w));
    }
}

// W'_l = (1-beta_l) I + beta_l W_l, all L layers at once.
__global__ __launch_bounds__(256) void prep_w(const float* __restrict__ conv_w,
                                              float* __restrict__ Wp, int total) {
    int i = blockIdx.x * blockDim.x + threadIdx.x;
    if (i >= total) return;
    int l = i >> 12;
    int r = i & 4095;
    int d = r >> 6, j = r & 63;
    float beta = logf(0.5f / (float)(l + 1) + 1.0f);
    float v = beta * conv_w[i];
    if (d == j) v += 1.0f - beta;
    Wp[i] = v;
}

// h0 = relu(x @ Wlin + b). Register-tiled GEMM. Writes x0, h (half).
__global__ __launch_bounds__(256) void lin0_kernel(
    const float* __restrict__ x, const float* __restrict__ Wlin,
    const float* __restrict__ b, ushort* __restrict__ x0,
    ushort* __restrict__ h, int n) {
    __shared__ float Ws[HH * DD];              // 32 KB
    __shared__ float xs[K_CHUNK][M_TILE + 4];
    for (int i = threadIdx.x; i < HH * DD; i += 256) Ws[i] = Wlin[i];

    int t = threadIdx.x;
    int tm = t >> 4, tn = t & 15;
    int m0 = blockIdx.x * M_TILE;

    float4 bb = *(const float4*)&b[tn * 4];
    float acc[8][4];
#pragma unroll
    for (int mi = 0; mi < 8; ++mi) {
        acc[mi][0] = bb.x; acc[mi][1] = bb.y; acc[mi][2] = bb.z; acc[mi][3] = bb.w;
    }

    for (int kk = 0; kk < HH; kk += K_CHUNK) {
        __syncthreads();
#pragma unroll
        for (int i = 0; i < 4; ++i) {
            int s = t + i * 256;
            int node = s >> 3;
            int cpos = (s & 7) * 4;
            int g = m0 + node;
            float4 v = make_float4(0.f, 0.f, 0.f, 0.f);
            if (g < n) v = *(const float4*)&x[(size_t)g * HH + kk + cpos];
            xs[cpos + 0][node] = v.x;
            xs[cpos + 1][node] = v.y;
            xs[cpos + 2][node] = v.z;
            xs[cpos + 3][node] = v.w;
        }
        __syncthreads();
#pragma unroll
        for (int k = 0; k < K_CHUNK; ++k) {
            float4 wv = *(const float4*)&Ws[(kk + k) * DD + tn * 4];
            const float* xr = &xs[k][tm * 8];
            float4 xa = *(const float4*)xr;
            float4 xb = *(const float4*)(xr + 4);
            float xm[8] = {xa.x, xa.y, xa.z, xa.w, xb.x, xb.y, xb.z, xb.w};
            float wj[4] = {wv.x, wv.y, wv.z, wv.w};
#pragma unroll
            for (int mi = 0; mi < 8; ++mi)
#pragma unroll
                for (int j = 0; j < 4; ++j)
                    acc[mi][j] += xm[mi] * wj[j];
        }
    }
#pragma unroll
    for (int mi = 0; mi < 8; ++mi) {
        int node = m0 + tm * 8 + mi;
        if (node >= n) continue;
        ushort4 o;
        o.x = f2h(fmaxf(acc[mi][0], 0.f));
        o.y = f2h(fmaxf(acc[mi][1], 0.f));
        o.z = f2h(fmaxf(acc[mi][2], 0.f));
        o.w = f2h(fmaxf(acc[mi][3], 0.f));
        *(ushort4*)&x0[(size_t)node * DD + tn * 4] = o;
        *(ushort4*)&h[(size_t)node * DD + tn * 4] = o;
    }
}

// Gather/SpMM: z = 0.9*(A@h) + 0.1*x0 (half storage). Group-per-node:
// each 16-lane group owns one node (4 nodes/wave). Per group: stage up to
// 16 edge records (one coalesced 128B load) into its LDS slot, then 4x4
// unrolled gathers with 4 accumulator sets -> 16 independent chains/wave.
// No cross-group combine; all 64 lanes write (4 nodes x 128B coalesced).
__global__ __launch_bounds__(256) void gather_kernel(
    const ushort* __restrict__ h_in, const ushort* __restrict__ x0,
    const int* __restrict__ rowptr, const int2* __restrict__ cw,
    ushort* __restrict__ z, int n) {
    __shared__ int2 es[4][64];
    int wave = threadIdx.x >> 6, lane = threadIdx.x & 63;
    int grp = lane >> 4, sub = lane & 15;
    int2* slot = &es[wave][grp * 16];

    for (int nb = (blockIdx.x * 4 + wave) * 4; nb < n; nb += gridDim.x * 16) {
        int node = nb + grp;
        bool nvalid = node < n;
        int nn = nvalid ? node : (n - 1);
        int beg = rowptr[nn];
        int end = nvalid ? rowptr[nn + 1] : beg;
        uint2 x0v = *(const uint2*)&x0[(size_t)nn * DD + sub * 4];
        float acc[4][4];
#pragma unroll
        for (int c = 0; c < 4; ++c)
#pragma unroll
            for (int f = 0; f < 4; ++f) acc[c][f] = 0.f;

        for (int base = beg; base < end; base += 16) {
            int m = end - base;
            if (m > 16) m = 16;
            if (sub < m) slot[sub] = cw[base + sub];
            // same-wave LDS write->read; compiler orders via lgkmcnt
#pragma unroll
            for (int j = 0; j < 4; ++j) {
#pragma unroll
                for (int c = 0; c < 4; ++c) {
                    int idx = j * 4 + c;
                    bool v = idx < m;
                    int2 r = slot[v ? idx : 0];
                    float w = v ? __int_as_float(r.y) : 0.f;
                    uint2 hv = *(const uint2*)&h_in[(size_t)r.x * DD + sub * 4];
                    acc[c][0] += w * us2f((ushort)(hv.x & 0xffff));
                    acc[c][1] += w * us2f((ushort)(hv.x >> 16));
                    acc[c][2] += w * us2f((ushort)(hv.y & 0xffff));
                    acc[c][3] += w * us2f((ushort)(hv.y >> 16));
                }
            }
        }
        float f0 = (acc[0][0] + acc[1][0]) + (acc[2][0] + acc[3][0]);
        float f1 = (acc[0][1] + acc[1][1]) + (acc[2][1] + acc[3][1]);
        float f2 = (acc[0][2] + acc[1][2]) + (acc[2][2] + acc[3][2]);
        float f3 = (acc[0][3] + acc[1][3]) + (acc[2][3] + acc[3][3]);
        if (nvalid) {
            float z0 = 0.9f * f0 + 0.1f * us2f((ushort)(x0v.x & 0xffff));
            float z1 = 0.9f * f1 + 0.1f * us2f((ushort)(x0v.x >> 16));
            float z2 = 0.9f * f2 + 0.1f * us2f((ushort)(x0v.y & 0xffff));
            float z3 = 0.9f * f3 + 0.1f * us2f((ushort)(x0v.y >> 16));
            uint zlo = (uint)f2h(z0) | ((uint)f2h(z1) << 16);
            uint zhi = (uint)f2h(z2) | ((uint)f2h(z3) << 16);
            *(uint2*)&z[(size_t)node * DD + sub * 4] = make_uint2(zlo, zhi);
        }
    }
}

// h = relu(z @ W'). Tiled GEMM, K=64. Output: half or f32 (final layer).
__global__ __launch_bounds__(256) void dense_kernel(
    const ushort* __restrict__ zin, const float* __restrict__ Wp,
    ushort* __restrict__ h_half, float* __restrict__ h_f32, int n) {
    __shared__ float Ws[DD * DD];
    __shared__ float xs[K_CHUNK][M_TILE + 4];
    for (int i = threadIdx.x; i < DD * DD; i += 256) Ws[i] = Wp[i];

    int t = threadIdx.x;
    int tm = t >> 4, tn = t & 15;
    int m0 = blockIdx.x * M_TILE;

    float acc[8][4];
#pragma unroll
    for (int mi = 0; mi < 8; ++mi)
#pragma unroll
        for (int j = 0; j < 4; ++j) acc[mi][j] = 0.f;

    for (int kk = 0; kk < DD; kk += K_CHUNK) {
        __syncthreads();
#pragma unroll
        for (int i = 0; i < 4; ++i) {
            int s = t + i * 256;
            int node = s >> 3;
            int cpos = (s & 7) * 4;
            int g = m0 + node;
            ushort4 v = make_ushort4(0, 0, 0, 0);
            if (g < n) v = *(const ushort4*)&zin[(size_t)g * DD + kk + cpos];
            xs[cpos + 0][node] = us2f(v.x);
            xs[cpos + 1][node] = us2f(v.y);
            xs[cpos + 2][node] = us2f(v.z);
            xs[cpos + 3][node] = us2f(v.w);
        }
        __syncthreads();
#pragma unroll
        for (int k = 0; k < K_CHUNK; ++k) {
            float4 wv = *(const float4*)&Ws[(kk + k) * DD + tn * 4];
            const float* xr = &xs[k][tm * 8];
            float4 xa = *(const float4*)xr;
            float4 xb = *(const float4*)(xr + 4);
            float xm[8] = {xa.x, xa.y, xa.z, xa.w, xb.x, xb.y, xb.z, xb.w};
            float wj[4] = {wv.x, wv.y, wv.z, wv.w};
#pragma unroll
            for (int mi = 0; mi < 8; ++mi)
#pragma unroll
                for (int j = 0; j < 4; ++j)
                    acc[mi][j] += xm[mi] * wj[j];
        }
    }
#pragma unroll
    for (int mi = 0; mi < 8; ++mi) {
        int node = m0 + tm * 8 + mi;
        if (node >= n) continue;
        float o0 = fmaxf(acc[mi][0], 0.f);
        float o1 = fmaxf(acc[mi][1], 0.f);
        float o2 = fmaxf(acc[mi][2], 0.f);
        float o3 = fmaxf(acc[mi][3], 0.f);
        if (h_f32) {
            *(float4*)&h_f32[(size_t)node * DD + tn * 4] =
                make_float4(o0, o1, o2, o3);
        } else {
            ushort4 o;
            o.x = f2h(o0); o.y = f2h(o1); o.z = f2h(o2); o.w = f2h(o3);
            *(ushort4*)&h_half[(size_t)node * DD + tn * 4] = o;
        }
    }
}

static inline size_t align256(size_t x) { return (x + 255) & ~(size_t)255; }

extern "C" void kernel_launch(void* const* d_in, const int* in_sizes, int n_in,
                              void* d_out, int out_size, void* d_ws, size_t ws_size,
                              hipStream_t stream) {
    const float* x      = (const float*)d_in[0];
    const int*   row    = (const int*)d_in[1];
    const int*   col    = (const int*)d_in[2];
    const float* ew     = (const float*)d_in[3];
    const float* w_lin  = (const float*)d_in[4];
    const float* b_lin  = (const float*)d_in[5];
    const float* conv_w = (const float*)d_in[6];
    float* out = (float*)d_out;

    const int N = in_sizes[0] / HH;          // 100000
    const int E = in_sizes[1];               // 1600000
    const int L = in_sizes[6] / (DD * DD);   // 4

    char* ws = (char*)d_ws;
    size_t off = 0;
    int* cnt = (int*)(ws + off);       off = align256(off + (size_t)N * 4);
    int* rowptr = (int*)(ws + off);    off = align256(off + (size_t)(N + 1) * 4);
    int* fill = (int*)(ws + off);      off = align256(off + (size_t)N * 4);
    int* bsum = (int*)(ws + off);      off = align256(off + 1024 * 4);
    int* bcnt = (int*)(ws + off);      off = align256(off + 8 * 4);
    int* boff = (int*)(ws + off);      off = align256(off + 9 * 4);
    int* bcur = (int*)(ws + off);      off = align256(off + 8 * 4);
    int2* cw = (int2*)(ws + off);      off = align256(off + (size_t)E * 8);
    ushort* x0 = (ushort*)(ws + off);  off = align256(off + (size_t)N * DD * 2);
    ushort* hA = (ushort*)(ws + off);  off = align256(off + (size_t)N * DD * 2);
    ushort* hB = (ushort*)(ws + off);  off = align256(off + (size_t)N * DD * 2);
    ushort* zb = (ushort*)(ws + off);  off = align256(off + (size_t)N * DD * 2);
    float* Wp = (float*)(ws + off);    off = align256(off + (size_t)L * DD * DD * 4);
    (void)ws_size;

    // pk0/pk1 (E*4 bytes each = 12.8MB total) alias hA (N*DD*2 = 12.8MB):
    // written by partition, consumed by hist/scatter, BEFORE lin0 writes hA.
    uint* pk0 = (uint*)hA;
    uint* pk1 = pk0 + E;

    const int nb = (N + SCAN_CHUNK - 1) / SCAN_CHUNK;
    const int mt = (N + M_TILE - 1) / M_TILE;

    // ---- CSR build: bucketed 3-phase sort ----
    zero_i32<<<(N + 255) / 256, 256, 0, stream>>>(cnt, N);
    hipMemsetAsync(bcnt, 0, 8 * sizeof(int), stream);
    bucket_count<<<1024, 256, 0, stream>>>(row, bcnt, E, N);
    bucket_scan<<<1, 64, 0, stream>>>(bcnt, boff, bcur);
    partition_kernel<<<1024, 256, 0, stream>>>(row, col, ew, bcur, pk0, pk1, E, N);
    hist_kernel<<<2048, 256, 0, stream>>>(pk0, boff, cnt);
    scanA<<<nb, 256, 0, stream>>>(cnt, bsum, N);
    scanB<<<1, 64, 0, stream>>>(bsum, nb, rowptr, N);
    scanC<<<nb, 256, 0, stream>>>(cnt, bsum, rowptr, fill, N);
    scatter_kernel<<<2048, 256, 0, stream>>>(pk0, pk1, boff, fill, cw);

    // ---- premixed layer weights ----
    int total = L * DD * DD;
    prep_w<<<(total + 255) / 256, 256, 0, stream>>>(conv_w, Wp, total);

    // ---- h0 = relu(x @ Wlin + b) -> x0, hA (half) ----
    lin0_kernel<<<mt, 256, 0, stream>>>(x, w_lin, b_lin, x0, hA, N);

    // ---- L layers: gather -> dense; ping-pong hA/hB; final -> f32 out ----
    for (int l = 0; l < L; ++l) {
        const ushort* hin = (l % 2 == 0) ? hA : hB;
        ushort* hout      = (l % 2 == 0) ? hB : hA;
        gather_kernel<<<2048, 256, 0, stream>>>(hin, x0, rowptr, cw, zb, N);
        bool last = (l == L - 1);
        dense_kernel<<<mt, 256, 0, stream>>>(zb, Wp + (size_t)l * DD * DD,
                                             last ? nullptr : hout,
                                             last ? out : nullptr, N);
    }
}